// Round 1
// baseline (893.543 us; speedup 1.0000x reference)
//
#include <hip/hip_runtime.h>
#include <hip/hip_bf16.h>

#define NNODES 100000
#define NEDGES 1600000
#define DF 128
#define NGRAPH 256

// ---------------- degree count (in-degree over real edges) ----------------
__global__ void deg_kernel(const int* __restrict__ dst, int* __restrict__ deg, int E) {
    int e = blockIdx.x * 256 + threadIdx.x;
    if (e < E) atomicAdd(&deg[dst[e]], 1);
}

// dinv[v] = rsqrt(deg[v] + 1)   (+1 = self loop; always >= 1)
__global__ void dinv_kernel(const int* __restrict__ deg, float* __restrict__ dinv, int n) {
    int v = blockIdx.x * 256 + threadIdx.x;
    if (v < n) dinv[v] = rsqrtf((float)deg[v] + 1.0f);
}

// single-block exclusive scan of (deg[v]+1) -> offs[0..n], offs[n] = total
__global__ void scan_kernel(const int* __restrict__ deg, int* __restrict__ offs, int n) {
    __shared__ int lds[1024];
    const int T = 1024;
    int t = threadIdx.x;
    int chunk = (n + T - 1) / T;
    int b = t * chunk, e = min(b + chunk, n);
    int s = 0;
    for (int i = b; i < e; i++) s += deg[i] + 1;
    lds[t] = s;
    __syncthreads();
    for (int off = 1; off < T; off <<= 1) {
        int v = lds[t];
        int add = (t >= off) ? lds[t - off] : 0;
        __syncthreads();
        lds[t] = v + add;
        __syncthreads();
    }
    int run = lds[t] - s;  // exclusive prefix of this chunk
    for (int i = b; i < e; i++) { offs[i] = run; run += deg[i] + 1; }
    if (t == T - 1) offs[n] = lds[T - 1];
}

__global__ void copy_cursor(const int* __restrict__ offs, int* __restrict__ cursor, int n) {
    int v = blockIdx.x * 256 + threadIdx.x;
    if (v < n) cursor[v] = offs[v];
}

__global__ void fill_edges(const int* __restrict__ src, const int* __restrict__ dst,
                           const float* __restrict__ dinv, int* __restrict__ cursor,
                           int* __restrict__ csrc, float* __restrict__ cnorm, int E) {
    int e = blockIdx.x * 256 + threadIdx.x;
    if (e >= E) return;
    int s = src[e], d0 = dst[e];
    int pos = atomicAdd(&cursor[d0], 1);
    csrc[pos] = s;
    cnorm[pos] = dinv[s] * dinv[d0];
}

__global__ void fill_self(const float* __restrict__ dinv, int* __restrict__ cursor,
                          int* __restrict__ csrc, float* __restrict__ cnorm, int n) {
    int v = blockIdx.x * 256 + threadIdx.x;
    if (v >= n) return;
    int pos = atomicAdd(&cursor[v], 1);
    csrc[pos] = v;
    cnorm[pos] = dinv[v] * dinv[v];
}

// ---------------- GEMM: C[n,128] = act(A (+bias_in)) @ W[128,128] ----------------
// block = 256 threads, 8 rows/block, each thread does 4 cols (float4).
// W staged in LDS in two 64-row halves (32 KB).
template <int RELU>
__global__ void gemm_kernel(const float* __restrict__ A, const float* __restrict__ W,
                            const float* __restrict__ bias_in, float* __restrict__ C) {
    __shared__ float Wl[64 * 128];
    int tid = threadIdx.x;
    int r = tid >> 5, cg = tid & 31;
    size_t row = (size_t)blockIdx.x * 8 + r;
    const float4* Wg4 = (const float4*)W;
    float4* Wl4 = (float4*)Wl;
    float4 acc = {0.f, 0.f, 0.f, 0.f};
    for (int half = 0; half < 2; ++half) {
        __syncthreads();
        for (int i = tid; i < 2048; i += 256) Wl4[i] = Wg4[half * 2048 + i];
        __syncthreads();
        int k0 = half * 64;
        #pragma unroll 8
        for (int kk = 0; kk < 64; ++kk) {
            float a = A[row * DF + k0 + kk];
            if (RELU) a = fmaxf(a + bias_in[k0 + kk], 0.f);
            float4 w = Wl4[kk * 32 + cg];
            acc.x += a * w.x; acc.y += a * w.y; acc.z += a * w.z; acc.w += a * w.w;
        }
    }
    ((float4*)C)[row * 32 + cg] = acc;
}

// ---------------- CSR aggregation: Out[v] = sum_{i in row v} norm[i]*H[src[i]] --------
// 32 lanes per node, 4 feats per lane, 8 nodes per 256-thread block.
__global__ void agg_kernel(const int* __restrict__ roff, const int* __restrict__ csrc,
                           const float* __restrict__ cnorm, const float* __restrict__ H,
                           float* __restrict__ Out) {
    int tid = threadIdx.x;
    int ln = tid >> 5, cg = tid & 31;
    size_t v = (size_t)blockIdx.x * 8 + ln;
    int b = roff[v], e = roff[v + 1];
    const float4* H4 = (const float4*)H;
    float4 acc = {0.f, 0.f, 0.f, 0.f};
    for (int i = b; i < e; i++) {
        int s = csrc[i];
        float nm = cnorm[i];
        float4 h = H4[(size_t)s * 32 + cg];
        acc.x += nm * h.x; acc.y += nm * h.y; acc.z += nm * h.z; acc.w += nm * h.w;
    }
    ((float4*)Out)[v * 32 + cg] = acc;
}

// ---------------- segmented mean-pool (batch sorted) ----------------
__global__ void pool_kernel(const float* __restrict__ H, const int* __restrict__ batch,
                            float* __restrict__ gsum, float* __restrict__ gcnt, int n) {
    __shared__ int bl[128];
    int d = threadIdx.x;
    int base = blockIdx.x * 128;
    int cnt_here = min(128, n - base);
    if (cnt_here <= 0) return;
    if (d < cnt_here) bl[d] = batch[base + d];
    __syncthreads();
    float acc = 0.f;
    int cg = -1, c = 0;
    for (int i = 0; i < cnt_here; i++) {
        int g = bl[i];
        if (g != cg) {
            if (cg >= 0) {
                atomicAdd(&gsum[cg * DF + d], acc);
                if (d == 0) atomicAdd(&gcnt[cg], (float)c);
            }
            acc = 0.f; c = 0; cg = g;
        }
        acc += H[(size_t)(base + i) * DF + d];
        c++;
    }
    if (cg >= 0) {
        atomicAdd(&gsum[cg * DF + d], acc);
        if (d == 0) atomicAdd(&gcnt[cg], (float)c);
    }
}

// ---------------- final: out[g] = dot(gsum[g]/cnt + b2, Wm) + bm ----------------
__global__ void final_kernel(const float* __restrict__ gsum, const float* __restrict__ gcnt,
                             const float* __restrict__ b2, const float* __restrict__ Wm,
                             const float* __restrict__ bm, float* __restrict__ out) {
    __shared__ float red[2];
    int g = blockIdx.x, d = threadIdx.x;
    float cnt = fmaxf(gcnt[g], 1.0f);
    float v = (gsum[g * DF + d] / cnt + b2[d]) * Wm[d];
    for (int off = 32; off > 0; off >>= 1) v += __shfl_down(v, off, 64);
    if ((d & 63) == 0) red[d >> 6] = v;
    __syncthreads();
    if (d == 0) out[g] = red[0] + red[1] + bm[0];
}

extern "C" void kernel_launch(void* const* d_in, const int* in_sizes, int n_in,
                              void* d_out, int out_size, void* d_ws, size_t ws_size,
                              hipStream_t stream) {
    const float* x   = (const float*)d_in[0];
    const int*   ei  = (const int*)d_in[1];   // [2, E] flat: first E = src, next E = dst
    const int*   bat = (const int*)d_in[2];
    const float* W1  = (const float*)d_in[3];
    const float* b1  = (const float*)d_in[4];
    const float* W2  = (const float*)d_in[5];
    const float* b2  = (const float*)d_in[6];
    const float* Wm  = (const float*)d_in[7];
    const float* bm  = (const float*)d_in[8];
    float* out = (float*)d_out;

    const int N = NNODES, E = NEDGES, G = NGRAPH;
    const int* src = ei;
    const int* dst = ei + E;

    // workspace carve
    char* base = (char*)d_ws;
    size_t o = 0;
    auto alloc = [&](size_t bytes) { size_t p = o; o = (o + bytes + 255) & ~(size_t)255; return p; };
    int*   deg    = (int*)(base + alloc((size_t)N * 4));
    int*   cursor = (int*)(base + alloc((size_t)N * 4));
    int*   offs   = (int*)(base + alloc((size_t)(N + 1) * 4));
    float* dinv   = (float*)(base + alloc((size_t)N * 4));
    int*   csrc   = (int*)(base + alloc((size_t)(E + N) * 4));
    float* cnorm  = (float*)(base + alloc((size_t)(E + N) * 4));
    float* bufA   = (float*)(base + alloc((size_t)N * DF * 4));
    float* bufB   = (float*)(base + alloc((size_t)N * DF * 4));
    float* gsum   = (float*)(base + alloc((size_t)G * DF * 4));
    float* gcnt   = (float*)(base + alloc((size_t)G * 4));
    (void)ws_size;

    hipMemsetAsync(deg, 0, (size_t)N * 4, stream);
    hipMemsetAsync(gsum, 0, (size_t)G * DF * 4, stream);
    hipMemsetAsync(gcnt, 0, (size_t)G * 4, stream);

    // CSR build
    deg_kernel<<<(E + 255) / 256, 256, 0, stream>>>(dst, deg, E);
    dinv_kernel<<<(N + 255) / 256, 256, 0, stream>>>(deg, dinv, N);
    scan_kernel<<<1, 1024, 0, stream>>>(deg, offs, N);
    copy_cursor<<<(N + 255) / 256, 256, 0, stream>>>(offs, cursor, N);
    fill_edges<<<(E + 255) / 256, 256, 0, stream>>>(src, dst, dinv, cursor, csrc, cnorm, E);
    fill_self<<<(N + 255) / 256, 256, 0, stream>>>(dinv, cursor, csrc, cnorm, N);

    // layer 1: bufA = x @ W1 ; bufB = A_hat * bufA
    gemm_kernel<0><<<N / 8, 256, 0, stream>>>(x, W1, nullptr, bufA);
    agg_kernel<<<N / 8, 256, 0, stream>>>(offs, csrc, cnorm, bufA, bufB);

    // layer 2: bufA = relu(bufB + b1) @ W2 ; bufB = A_hat * bufA
    gemm_kernel<1><<<N / 8, 256, 0, stream>>>(bufB, W2, b1, bufA);
    agg_kernel<<<N / 8, 256, 0, stream>>>(offs, csrc, cnorm, bufA, bufB);

    // pool + final
    pool_kernel<<<(N + 127) / 128, 128, 0, stream>>>(bufB, bat, gsum, gcnt, N);
    final_kernel<<<G, 128, 0, stream>>>(gsum, gcnt, b2, Wm, bm, out);
}

// Round 2
// 601.684 us; speedup vs baseline: 1.4851x; 1.4851x over previous
//
#include <hip/hip_runtime.h>
#include <hip/hip_bf16.h>

#define NNODES 100000
#define NEDGES 1600000
#define DF 128
#define NGRAPH 256
#define SCAN_CHUNK 2048
#define NB_SCAN ((NNODES + SCAN_CHUNK - 1) / SCAN_CHUNK)

// ---------------- degree count (in-degree over real edges) ----------------
__global__ void deg_kernel(const int* __restrict__ dst, int* __restrict__ deg, int E) {
    int e = blockIdx.x * 256 + threadIdx.x;
    if (e < E) atomicAdd(&deg[dst[e]], 1);
}

// dinv[v] = rsqrt(deg[v] + 1)   (+1 = self loop; always >= 1)
__global__ void dinv_kernel(const int* __restrict__ deg, float* __restrict__ dinv, int n) {
    int v = blockIdx.x * 256 + threadIdx.x;
    if (v < n) dinv[v] = rsqrtf((float)deg[v] + 1.0f);
}

// ---------------- hierarchical scan of (deg[v]+1) -> offs[0..n], cursor ----------------
// scan1: per-block (2048 elems) sums
__global__ void scan1_kernel(const int* __restrict__ deg, int* __restrict__ psum, int n) {
    __shared__ int lds[256];
    int t = threadIdx.x;
    int base = blockIdx.x * SCAN_CHUNK + t * 8;
    int s = 0;
    #pragma unroll
    for (int i = 0; i < 8; i++) { int idx = base + i; if (idx < n) s += deg[idx] + 1; }
    lds[t] = s;
    __syncthreads();
    for (int off = 128; off > 0; off >>= 1) {
        if (t < off) lds[t] += lds[t + off];
        __syncthreads();
    }
    if (t == 0) psum[blockIdx.x] = lds[0];
}

// scan2: single small block scans the ~49 partials; writes offs[n] = total
__global__ void scan2_kernel(int* __restrict__ psum, int* __restrict__ offs, int nb, int n) {
    __shared__ int lds[64];
    int t = threadIdx.x;  // 64 threads
    int v = (t < nb) ? psum[t] : 0;
    lds[t] = v;
    __syncthreads();
    for (int off = 1; off < 64; off <<= 1) {
        int x = lds[t];
        int add = (t >= off) ? lds[t - off] : 0;
        __syncthreads();
        lds[t] = x + add;
        __syncthreads();
    }
    if (t < nb) psum[t] = lds[t] - v;  // exclusive prefix of block sums
    if (t == 63) offs[n] = lds[63];    // grand total
}

// scan3: local exclusive scan + block prefix; writes offs[] and cursor[]
__global__ void scan3_kernel(const int* __restrict__ deg, const int* __restrict__ psum,
                             int* __restrict__ offs, int* __restrict__ cursor, int n) {
    __shared__ int lds[256];
    int t = threadIdx.x;
    int base = blockIdx.x * SCAN_CHUNK + t * 8;
    int dv[8];
    int s = 0;
    #pragma unroll
    for (int i = 0; i < 8; i++) {
        int idx = base + i;
        dv[i] = (idx < n) ? deg[idx] + 1 : 0;
        s += dv[i];
    }
    lds[t] = s;
    __syncthreads();
    for (int off = 1; off < 256; off <<= 1) {
        int x = lds[t];
        int add = (t >= off) ? lds[t - off] : 0;
        __syncthreads();
        lds[t] = x + add;
        __syncthreads();
    }
    int run = psum[blockIdx.x] + lds[t] - s;  // exclusive prefix for this thread
    #pragma unroll
    for (int i = 0; i < 8; i++) {
        int idx = base + i;
        if (idx < n) { offs[idx] = run; cursor[idx] = run; run += dv[i]; }
    }
}

__global__ void fill_edges(const int* __restrict__ src, const int* __restrict__ dst,
                           const float* __restrict__ dinv, int* __restrict__ cursor,
                           int* __restrict__ csrc, float* __restrict__ cnorm, int E) {
    int e = blockIdx.x * 256 + threadIdx.x;
    if (e >= E) return;
    int s = src[e], d0 = dst[e];
    int pos = atomicAdd(&cursor[d0], 1);
    csrc[pos] = s;
    cnorm[pos] = dinv[s] * dinv[d0];
}

__global__ void fill_self(const float* __restrict__ dinv, int* __restrict__ cursor,
                          int* __restrict__ csrc, float* __restrict__ cnorm, int n) {
    int v = blockIdx.x * 256 + threadIdx.x;
    if (v >= n) return;
    int pos = atomicAdd(&cursor[v], 1);
    csrc[pos] = v;
    cnorm[pos] = dinv[v] * dinv[v];
}

// ---------------- GEMM: C[n,128] = A @ W[128,128] ----------------
// block = 256 threads covering 32 rows; each thread: 4 rows x 4 cols.
// W staged in LDS in two 64-row halves (32 KB); each ds_read_b128 feeds 16 FMAs.
__global__ void gemm_kernel(const float* __restrict__ A, const float* __restrict__ W,
                            float* __restrict__ C) {
    __shared__ float Wl[64 * 128];
    int tid = threadIdx.x;
    int rg = tid >> 5, cg = tid & 31;
    size_t row0 = (size_t)blockIdx.x * 32 + rg;  // rows row0 + {0,8,16,24}
    const float4* Wg4 = (const float4*)W;
    const float4* A4 = (const float4*)A;
    float4* Wl4 = (float4*)Wl;
    float4 acc0 = {0.f,0.f,0.f,0.f}, acc1 = acc0, acc2 = acc0, acc3 = acc0;
    for (int half = 0; half < 2; ++half) {
        __syncthreads();
        for (int i = tid; i < 2048; i += 256) Wl4[i] = Wg4[half * 2048 + i];
        __syncthreads();
        #pragma unroll
        for (int kq = 0; kq < 16; ++kq) {
            int kv = half * 16 + kq;  // float4 index within A row
            float4 a0 = A4[(row0 + 0)  * 32 + kv];
            float4 a1 = A4[(row0 + 8)  * 32 + kv];
            float4 a2 = A4[(row0 + 16) * 32 + kv];
            float4 a3 = A4[(row0 + 24) * 32 + kv];
            float a0v[4] = {a0.x, a0.y, a0.z, a0.w};
            float a1v[4] = {a1.x, a1.y, a1.z, a1.w};
            float a2v[4] = {a2.x, a2.y, a2.z, a2.w};
            float a3v[4] = {a3.x, a3.y, a3.z, a3.w};
            #pragma unroll
            for (int j = 0; j < 4; ++j) {
                float4 w = Wl4[(kq * 4 + j) * 32 + cg];
                acc0.x += a0v[j]*w.x; acc0.y += a0v[j]*w.y; acc0.z += a0v[j]*w.z; acc0.w += a0v[j]*w.w;
                acc1.x += a1v[j]*w.x; acc1.y += a1v[j]*w.y; acc1.z += a1v[j]*w.z; acc1.w += a1v[j]*w.w;
                acc2.x += a2v[j]*w.x; acc2.y += a2v[j]*w.y; acc2.z += a2v[j]*w.z; acc2.w += a2v[j]*w.w;
                acc3.x += a3v[j]*w.x; acc3.y += a3v[j]*w.y; acc3.z += a3v[j]*w.z; acc3.w += a3v[j]*w.w;
            }
        }
    }
    float4* C4 = (float4*)C;
    C4[(row0 + 0)  * 32 + cg] = acc0;
    C4[(row0 + 8)  * 32 + cg] = acc1;
    C4[(row0 + 16) * 32 + cg] = acc2;
    C4[(row0 + 24) * 32 + cg] = acc3;
}

// ---------------- CSR aggregation: Out[v] = epilogue(sum norm[i]*H[src[i]]) --------
// 32 lanes per node, 4 feats per lane, 8 nodes per 256-thread block.
template <int BIAS_RELU>
__global__ void agg_kernel(const int* __restrict__ roff, const int* __restrict__ csrc,
                           const float* __restrict__ cnorm, const float* __restrict__ H,
                           const float* __restrict__ bias, float* __restrict__ Out) {
    int tid = threadIdx.x;
    int ln = tid >> 5, cg = tid & 31;
    size_t v = (size_t)blockIdx.x * 8 + ln;
    int b = roff[v], e = roff[v + 1];
    const float4* H4 = (const float4*)H;
    float4 acc = {0.f, 0.f, 0.f, 0.f};
    for (int i = b; i < e; i++) {
        int s = csrc[i];
        float nm = cnorm[i];
        float4 h = H4[(size_t)s * 32 + cg];
        acc.x += nm * h.x; acc.y += nm * h.y; acc.z += nm * h.z; acc.w += nm * h.w;
    }
    if (BIAS_RELU) {
        float4 bb = ((const float4*)bias)[cg];
        acc.x = fmaxf(acc.x + bb.x, 0.f);
        acc.y = fmaxf(acc.y + bb.y, 0.f);
        acc.z = fmaxf(acc.z + bb.z, 0.f);
        acc.w = fmaxf(acc.w + bb.w, 0.f);
    }
    ((float4*)Out)[v * 32 + cg] = acc;
}

// ---------------- segmented mean-pool (batch sorted) ----------------
__global__ void pool_kernel(const float* __restrict__ H, const int* __restrict__ batch,
                            float* __restrict__ gsum, float* __restrict__ gcnt, int n) {
    __shared__ int bl[128];
    int d = threadIdx.x;
    int base = blockIdx.x * 128;
    int cnt_here = min(128, n - base);
    if (cnt_here <= 0) return;
    if (d < cnt_here) bl[d] = batch[base + d];
    __syncthreads();
    float acc = 0.f;
    int cg = -1, c = 0;
    for (int i = 0; i < cnt_here; i++) {
        int g = bl[i];
        if (g != cg) {
            if (cg >= 0) {
                atomicAdd(&gsum[cg * DF + d], acc);
                if (d == 0) atomicAdd(&gcnt[cg], (float)c);
            }
            acc = 0.f; c = 0; cg = g;
        }
        acc += H[(size_t)(base + i) * DF + d];
        c++;
    }
    if (cg >= 0) {
        atomicAdd(&gsum[cg * DF + d], acc);
        if (d == 0) atomicAdd(&gcnt[cg], (float)c);
    }
}

// ---------------- final: out[g] = dot(gsum[g]/cnt + b2, Wm) + bm ----------------
__global__ void final_kernel(const float* __restrict__ gsum, const float* __restrict__ gcnt,
                             const float* __restrict__ b2, const float* __restrict__ Wm,
                             const float* __restrict__ bm, float* __restrict__ out) {
    __shared__ float red[2];
    int g = blockIdx.x, d = threadIdx.x;
    float cnt = fmaxf(gcnt[g], 1.0f);
    float v = (gsum[g * DF + d] / cnt + b2[d]) * Wm[d];
    for (int off = 32; off > 0; off >>= 1) v += __shfl_down(v, off, 64);
    if ((d & 63) == 0) red[d >> 6] = v;
    __syncthreads();
    if (d == 0) out[g] = red[0] + red[1] + bm[0];
}

extern "C" void kernel_launch(void* const* d_in, const int* in_sizes, int n_in,
                              void* d_out, int out_size, void* d_ws, size_t ws_size,
                              hipStream_t stream) {
    const float* x   = (const float*)d_in[0];
    const int*   ei  = (const int*)d_in[1];   // [2, E] flat: first E = src, next E = dst
    const int*   bat = (const int*)d_in[2];
    const float* W1  = (const float*)d_in[3];
    const float* b1  = (const float*)d_in[4];
    const float* W2  = (const float*)d_in[5];
    const float* b2  = (const float*)d_in[6];
    const float* Wm  = (const float*)d_in[7];
    const float* bm  = (const float*)d_in[8];
    float* out = (float*)d_out;

    const int N = NNODES, E = NEDGES, G = NGRAPH;
    const int* src = ei;
    const int* dst = ei + E;

    // workspace carve
    char* base = (char*)d_ws;
    size_t o = 0;
    auto alloc = [&](size_t bytes) { size_t p = o; o = (o + bytes + 255) & ~(size_t)255; return p; };
    int*   deg    = (int*)(base + alloc((size_t)N * 4));
    int*   cursor = (int*)(base + alloc((size_t)N * 4));
    int*   offs   = (int*)(base + alloc((size_t)(N + 1) * 4));
    float* dinv   = (float*)(base + alloc((size_t)N * 4));
    int*   psum   = (int*)(base + alloc((size_t)NB_SCAN * 4));
    int*   csrc   = (int*)(base + alloc((size_t)(E + N) * 4));
    float* cnorm  = (float*)(base + alloc((size_t)(E + N) * 4));
    float* bufA   = (float*)(base + alloc((size_t)N * DF * 4));
    float* bufB   = (float*)(base + alloc((size_t)N * DF * 4));
    float* gsum   = (float*)(base + alloc((size_t)G * DF * 4));
    float* gcnt   = (float*)(base + alloc((size_t)G * 4));
    (void)ws_size;

    hipMemsetAsync(deg, 0, (size_t)N * 4, stream);
    hipMemsetAsync(gsum, 0, (size_t)G * DF * 4, stream);
    hipMemsetAsync(gcnt, 0, (size_t)G * 4, stream);

    // CSR build
    deg_kernel<<<(E + 255) / 256, 256, 0, stream>>>(dst, deg, E);
    dinv_kernel<<<(N + 255) / 256, 256, 0, stream>>>(deg, dinv, N);
    scan1_kernel<<<NB_SCAN, 256, 0, stream>>>(deg, psum, N);
    scan2_kernel<<<1, 64, 0, stream>>>(psum, offs, NB_SCAN, N);
    scan3_kernel<<<NB_SCAN, 256, 0, stream>>>(deg, psum, offs, cursor, N);
    fill_edges<<<(E + 255) / 256, 256, 0, stream>>>(src, dst, dinv, cursor, csrc, cnorm, E);
    fill_self<<<(N + 255) / 256, 256, 0, stream>>>(dinv, cursor, csrc, cnorm, N);

    // layer 1: bufA = x @ W1 ; bufB = relu(A_hat * bufA + b1)
    gemm_kernel<<<N / 32, 256, 0, stream>>>(x, W1, bufA);
    agg_kernel<1><<<N / 8, 256, 0, stream>>>(offs, csrc, cnorm, bufA, b1, bufB);

    // layer 2: bufA = bufB @ W2 ; bufB = A_hat * bufA
    gemm_kernel<<<N / 32, 256, 0, stream>>>(bufB, W2, bufA);
    agg_kernel<0><<<N / 8, 256, 0, stream>>>(offs, csrc, cnorm, bufA, nullptr, bufB);

    // pool + final
    pool_kernel<<<(N + 127) / 128, 128, 0, stream>>>(bufB, bat, gsum, gcnt, N);
    final_kernel<<<G, 128, 0, stream>>>(gsum, gcnt, b2, Wm, bm, out);
}

// Round 3
// 579.310 us; speedup vs baseline: 1.5424x; 1.0386x over previous
//
#include <hip/hip_runtime.h>
#include <hip/hip_bf16.h>

#define NNODES 100000
#define NEDGES 1600000
#define DF 128
#define NGRAPH 256
#define SCAN_CHUNK 2048
#define NB_SCAN ((NNODES + SCAN_CHUNK - 1) / SCAN_CHUNK)

// ---------------- degree count (in-degree over real edges) ----------------
__global__ void deg_kernel(const int* __restrict__ dst, int* __restrict__ deg, int E) {
    int e = blockIdx.x * 256 + threadIdx.x;
    if (e < E) atomicAdd(&deg[dst[e]], 1);
}

// dinv[v] = rsqrt(deg[v] + 1)   (+1 = self loop; always >= 1)
__global__ void dinv_kernel(const int* __restrict__ deg, float* __restrict__ dinv, int n) {
    int v = blockIdx.x * 256 + threadIdx.x;
    if (v < n) dinv[v] = rsqrtf((float)deg[v] + 1.0f);
}

// ---------------- hierarchical scan of (deg[v]+1) -> offs[0..n], cursor ----------------
__global__ void scan1_kernel(const int* __restrict__ deg, int* __restrict__ psum, int n) {
    __shared__ int lds[256];
    int t = threadIdx.x;
    int base = blockIdx.x * SCAN_CHUNK + t * 8;
    int s = 0;
    #pragma unroll
    for (int i = 0; i < 8; i++) { int idx = base + i; if (idx < n) s += deg[idx] + 1; }
    lds[t] = s;
    __syncthreads();
    for (int off = 128; off > 0; off >>= 1) {
        if (t < off) lds[t] += lds[t + off];
        __syncthreads();
    }
    if (t == 0) psum[blockIdx.x] = lds[0];
}

__global__ void scan2_kernel(int* __restrict__ psum, int* __restrict__ offs, int nb, int n) {
    __shared__ int lds[64];
    int t = threadIdx.x;  // 64 threads
    int v = (t < nb) ? psum[t] : 0;
    lds[t] = v;
    __syncthreads();
    for (int off = 1; off < 64; off <<= 1) {
        int x = lds[t];
        int add = (t >= off) ? lds[t - off] : 0;
        __syncthreads();
        lds[t] = x + add;
        __syncthreads();
    }
    if (t < nb) psum[t] = lds[t] - v;  // exclusive prefix of block sums
    if (t == 63) offs[n] = lds[63];    // grand total
}

__global__ void scan3_kernel(const int* __restrict__ deg, const int* __restrict__ psum,
                             int* __restrict__ offs, int* __restrict__ cursor, int n) {
    __shared__ int lds[256];
    int t = threadIdx.x;
    int base = blockIdx.x * SCAN_CHUNK + t * 8;
    int dv[8];
    int s = 0;
    #pragma unroll
    for (int i = 0; i < 8; i++) {
        int idx = base + i;
        dv[i] = (idx < n) ? deg[idx] + 1 : 0;
        s += dv[i];
    }
    lds[t] = s;
    __syncthreads();
    for (int off = 1; off < 256; off <<= 1) {
        int x = lds[t];
        int add = (t >= off) ? lds[t - off] : 0;
        __syncthreads();
        lds[t] = x + add;
        __syncthreads();
    }
    int run = psum[blockIdx.x] + lds[t] - s;
    #pragma unroll
    for (int i = 0; i < 8; i++) {
        int idx = base + i;
        if (idx < n) { offs[idx] = run; cursor[idx] = run; run += dv[i]; }
    }
}

// packed edge record: .x = src node, .y = bitcast(norm)
__global__ void fill_edges(const int* __restrict__ src, const int* __restrict__ dst,
                           const float* __restrict__ dinv, int* __restrict__ cursor,
                           int2* __restrict__ cpk, int E) {
    int e = blockIdx.x * 256 + threadIdx.x;
    if (e >= E) return;
    int s = src[e], d0 = dst[e];
    int pos = atomicAdd(&cursor[d0], 1);
    cpk[pos] = make_int2(s, __float_as_int(dinv[s] * dinv[d0]));
}

__global__ void fill_self(const float* __restrict__ dinv, int* __restrict__ cursor,
                          int2* __restrict__ cpk, int n) {
    int v = blockIdx.x * 256 + threadIdx.x;
    if (v >= n) return;
    int pos = atomicAdd(&cursor[v], 1);
    float dv = dinv[v];
    cpk[pos] = make_int2(v, __float_as_int(dv * dv));
}

// ---------------- GEMM: C[n,128] = A @ W[128,128] ----------------
__global__ void gemm_kernel(const float* __restrict__ A, const float* __restrict__ W,
                            float* __restrict__ C) {
    __shared__ float Wl[64 * 128];
    int tid = threadIdx.x;
    int rg = tid >> 5, cg = tid & 31;
    size_t row0 = (size_t)blockIdx.x * 32 + rg;  // rows row0 + {0,8,16,24}
    const float4* Wg4 = (const float4*)W;
    const float4* A4 = (const float4*)A;
    float4* Wl4 = (float4*)Wl;
    float4 acc0 = {0.f,0.f,0.f,0.f}, acc1 = acc0, acc2 = acc0, acc3 = acc0;
    for (int half = 0; half < 2; ++half) {
        __syncthreads();
        for (int i = tid; i < 2048; i += 256) Wl4[i] = Wg4[half * 2048 + i];
        __syncthreads();
        #pragma unroll
        for (int kq = 0; kq < 16; ++kq) {
            int kv = half * 16 + kq;
            float4 a0 = A4[(row0 + 0)  * 32 + kv];
            float4 a1 = A4[(row0 + 8)  * 32 + kv];
            float4 a2 = A4[(row0 + 16) * 32 + kv];
            float4 a3 = A4[(row0 + 24) * 32 + kv];
            float a0v[4] = {a0.x, a0.y, a0.z, a0.w};
            float a1v[4] = {a1.x, a1.y, a1.z, a1.w};
            float a2v[4] = {a2.x, a2.y, a2.z, a2.w};
            float a3v[4] = {a3.x, a3.y, a3.z, a3.w};
            #pragma unroll
            for (int j = 0; j < 4; ++j) {
                float4 w = Wl4[(kq * 4 + j) * 32 + cg];
                acc0.x += a0v[j]*w.x; acc0.y += a0v[j]*w.y; acc0.z += a0v[j]*w.z; acc0.w += a0v[j]*w.w;
                acc1.x += a1v[j]*w.x; acc1.y += a1v[j]*w.y; acc1.z += a1v[j]*w.z; acc1.w += a1v[j]*w.w;
                acc2.x += a2v[j]*w.x; acc2.y += a2v[j]*w.y; acc2.z += a2v[j]*w.z; acc2.w += a2v[j]*w.w;
                acc3.x += a3v[j]*w.x; acc3.y += a3v[j]*w.y; acc3.z += a3v[j]*w.z; acc3.w += a3v[j]*w.w;
            }
        }
    }
    float4* C4 = (float4*)C;
    C4[(row0 + 0)  * 32 + cg] = acc0;
    C4[(row0 + 8)  * 32 + cg] = acc1;
    C4[(row0 + 16) * 32 + cg] = acc2;
    C4[(row0 + 24) * 32 + cg] = acc3;
}

// ---------------- CSR aggregation: Out[v] = epilogue(sum norm[i]*H[src[i]]) --------
// 16 lanes per node (each lane owns 8 feats = 2 float4), 16 nodes per 256-thread block.
// Edge loop unrolled x2 -> 4 independent gathers + 2 packed index loads in flight.
template <int BIAS_RELU>
__global__ void agg_kernel(const int* __restrict__ roff, const int2* __restrict__ cpk,
                           const float* __restrict__ H, const float* __restrict__ bias,
                           float* __restrict__ Out) {
    int tid = threadIdx.x;
    int ln = tid >> 4, cg = tid & 15;
    size_t v = (size_t)blockIdx.x * 16 + ln;
    int b = roff[v], e = roff[v + 1];
    const float4* H4 = (const float4*)H;
    float4 acc0 = {0.f, 0.f, 0.f, 0.f}, acc1 = acc0;
    int i = b;
    for (; i + 2 <= e; i += 2) {
        int2 p0 = cpk[i];
        int2 p1 = cpk[i + 1];
        size_t s0 = (size_t)p0.x, s1 = (size_t)p1.x;
        float n0 = __int_as_float(p0.y), n1 = __int_as_float(p1.y);
        float4 h00 = H4[s0 * 32 + cg];
        float4 h01 = H4[s0 * 32 + 16 + cg];
        float4 h10 = H4[s1 * 32 + cg];
        float4 h11 = H4[s1 * 32 + 16 + cg];
        acc0.x += n0 * h00.x + n1 * h10.x; acc0.y += n0 * h00.y + n1 * h10.y;
        acc0.z += n0 * h00.z + n1 * h10.z; acc0.w += n0 * h00.w + n1 * h10.w;
        acc1.x += n0 * h01.x + n1 * h11.x; acc1.y += n0 * h01.y + n1 * h11.y;
        acc1.z += n0 * h01.z + n1 * h11.z; acc1.w += n0 * h01.w + n1 * h11.w;
    }
    if (i < e) {
        int2 p0 = cpk[i];
        size_t s0 = (size_t)p0.x;
        float n0 = __int_as_float(p0.y);
        float4 h00 = H4[s0 * 32 + cg];
        float4 h01 = H4[s0 * 32 + 16 + cg];
        acc0.x += n0 * h00.x; acc0.y += n0 * h00.y; acc0.z += n0 * h00.z; acc0.w += n0 * h00.w;
        acc1.x += n0 * h01.x; acc1.y += n0 * h01.y; acc1.z += n0 * h01.z; acc1.w += n0 * h01.w;
    }
    if (BIAS_RELU) {
        float4 b0 = ((const float4*)bias)[cg];
        float4 b1 = ((const float4*)bias)[16 + cg];
        acc0.x = fmaxf(acc0.x + b0.x, 0.f); acc0.y = fmaxf(acc0.y + b0.y, 0.f);
        acc0.z = fmaxf(acc0.z + b0.z, 0.f); acc0.w = fmaxf(acc0.w + b0.w, 0.f);
        acc1.x = fmaxf(acc1.x + b1.x, 0.f); acc1.y = fmaxf(acc1.y + b1.y, 0.f);
        acc1.z = fmaxf(acc1.z + b1.z, 0.f); acc1.w = fmaxf(acc1.w + b1.w, 0.f);
    }
    float4* O4 = (float4*)Out;
    O4[v * 32 + cg] = acc0;
    O4[v * 32 + 16 + cg] = acc1;
}

// ---------------- segmented mean-pool (batch sorted) ----------------
__global__ void pool_kernel(const float* __restrict__ H, const int* __restrict__ batch,
                            float* __restrict__ gsum, float* __restrict__ gcnt, int n) {
    __shared__ int bl[128];
    int d = threadIdx.x;
    int base = blockIdx.x * 128;
    int cnt_here = min(128, n - base);
    if (cnt_here <= 0) return;
    if (d < cnt_here) bl[d] = batch[base + d];
    __syncthreads();
    float acc = 0.f;
    int cg = -1, c = 0;
    for (int i = 0; i < cnt_here; i++) {
        int g = bl[i];
        if (g != cg) {
            if (cg >= 0) {
                atomicAdd(&gsum[cg * DF + d], acc);
                if (d == 0) atomicAdd(&gcnt[cg], (float)c);
            }
            acc = 0.f; c = 0; cg = g;
        }
        acc += H[(size_t)(base + i) * DF + d];
        c++;
    }
    if (cg >= 0) {
        atomicAdd(&gsum[cg * DF + d], acc);
        if (d == 0) atomicAdd(&gcnt[cg], (float)c);
    }
}

// ---------------- final: out[g] = dot(gsum[g]/cnt + b2, Wm) + bm ----------------
__global__ void final_kernel(const float* __restrict__ gsum, const float* __restrict__ gcnt,
                             const float* __restrict__ b2, const float* __restrict__ Wm,
                             const float* __restrict__ bm, float* __restrict__ out) {
    __shared__ float red[2];
    int g = blockIdx.x, d = threadIdx.x;
    float cnt = fmaxf(gcnt[g], 1.0f);
    float v = (gsum[g * DF + d] / cnt + b2[d]) * Wm[d];
    for (int off = 32; off > 0; off >>= 1) v += __shfl_down(v, off, 64);
    if ((d & 63) == 0) red[d >> 6] = v;
    __syncthreads();
    if (d == 0) out[g] = red[0] + red[1] + bm[0];
}

extern "C" void kernel_launch(void* const* d_in, const int* in_sizes, int n_in,
                              void* d_out, int out_size, void* d_ws, size_t ws_size,
                              hipStream_t stream) {
    const float* x   = (const float*)d_in[0];
    const int*   ei  = (const int*)d_in[1];   // [2, E] flat: first E = src, next E = dst
    const int*   bat = (const int*)d_in[2];
    const float* W1  = (const float*)d_in[3];
    const float* b1  = (const float*)d_in[4];
    const float* W2  = (const float*)d_in[5];
    const float* b2  = (const float*)d_in[6];
    const float* Wm  = (const float*)d_in[7];
    const float* bm  = (const float*)d_in[8];
    float* out = (float*)d_out;

    const int N = NNODES, E = NEDGES, G = NGRAPH;
    const int* src = ei;
    const int* dst = ei + E;

    // workspace carve
    char* base = (char*)d_ws;
    size_t o = 0;
    auto alloc = [&](size_t bytes) { size_t p = o; o = (o + bytes + 255) & ~(size_t)255; return p; };
    int*   deg    = (int*)(base + alloc((size_t)N * 4));
    int*   cursor = (int*)(base + alloc((size_t)N * 4));
    int*   offs   = (int*)(base + alloc((size_t)(N + 1) * 4));
    float* dinv   = (float*)(base + alloc((size_t)N * 4));
    int*   psum   = (int*)(base + alloc((size_t)NB_SCAN * 4));
    int2*  cpk    = (int2*)(base + alloc((size_t)(E + N) * 8));
    float* bufA   = (float*)(base + alloc((size_t)N * DF * 4));
    float* bufB   = (float*)(base + alloc((size_t)N * DF * 4));
    float* gsum   = (float*)(base + alloc((size_t)G * DF * 4));
    float* gcnt   = (float*)(base + alloc((size_t)G * 4));
    (void)ws_size;

    hipMemsetAsync(deg, 0, (size_t)N * 4, stream);
    hipMemsetAsync(gsum, 0, (size_t)G * DF * 4, stream);
    hipMemsetAsync(gcnt, 0, (size_t)G * 4, stream);

    // CSR build
    deg_kernel<<<(E + 255) / 256, 256, 0, stream>>>(dst, deg, E);
    dinv_kernel<<<(N + 255) / 256, 256, 0, stream>>>(deg, dinv, N);
    scan1_kernel<<<NB_SCAN, 256, 0, stream>>>(deg, psum, N);
    scan2_kernel<<<1, 64, 0, stream>>>(psum, offs, NB_SCAN, N);
    scan3_kernel<<<NB_SCAN, 256, 0, stream>>>(deg, psum, offs, cursor, N);
    fill_edges<<<(E + 255) / 256, 256, 0, stream>>>(src, dst, dinv, cursor, cpk, E);
    fill_self<<<(N + 255) / 256, 256, 0, stream>>>(dinv, cursor, cpk, N);

    // layer 1: bufA = x @ W1 ; bufB = relu(A_hat * bufA + b1)
    gemm_kernel<<<N / 32, 256, 0, stream>>>(x, W1, bufA);
    agg_kernel<1><<<(N + 15) / 16, 256, 0, stream>>>(offs, cpk, bufA, b1, bufB);

    // layer 2: bufA = bufB @ W2 ; bufB = A_hat * bufA
    gemm_kernel<<<N / 32, 256, 0, stream>>>(bufB, W2, bufA);
    agg_kernel<0><<<(N + 15) / 16, 256, 0, stream>>>(offs, cpk, bufA, nullptr, bufB);

    // pool + final
    pool_kernel<<<(N + 127) / 128, 128, 0, stream>>>(bufB, bat, gsum, gcnt, N);
    final_kernel<<<G, 128, 0, stream>>>(gsum, gcnt, b2, Wm, bm, out);
}

// Round 4
// 563.875 us; speedup vs baseline: 1.5846x; 1.0274x over previous
//
#include <hip/hip_runtime.h>
#include <hip/hip_bf16.h>

#define NNODES 100000
#define NEDGES 1600000
#define DF 128
#define NGRAPH 256
#define SCAN_CHUNK 2048
#define NB_SCAN ((NNODES + SCAN_CHUNK - 1) / SCAN_CHUNK)

// ---------------- degree count (in-degree over real edges) ----------------
__global__ void deg_kernel(const int* __restrict__ dst, int* __restrict__ deg, int E) {
    int e = blockIdx.x * 256 + threadIdx.x;
    if (e < E) atomicAdd(&deg[dst[e]], 1);
}

// dinv[v] = rsqrt(deg[v] + 1)   (+1 = self loop; always >= 1)
__global__ void dinv_kernel(const int* __restrict__ deg, float* __restrict__ dinv, int n) {
    int v = blockIdx.x * 256 + threadIdx.x;
    if (v < n) dinv[v] = rsqrtf((float)deg[v] + 1.0f);
}

// ---------------- hierarchical scan of (deg[v]+1) -> offs[0..n], cursor ----------------
__global__ void scan1_kernel(const int* __restrict__ deg, int* __restrict__ psum, int n) {
    __shared__ int lds[256];
    int t = threadIdx.x;
    int base = blockIdx.x * SCAN_CHUNK + t * 8;
    int s = 0;
    #pragma unroll
    for (int i = 0; i < 8; i++) { int idx = base + i; if (idx < n) s += deg[idx] + 1; }
    lds[t] = s;
    __syncthreads();
    for (int off = 128; off > 0; off >>= 1) {
        if (t < off) lds[t] += lds[t + off];
        __syncthreads();
    }
    if (t == 0) psum[blockIdx.x] = lds[0];
}

__global__ void scan2_kernel(int* __restrict__ psum, int* __restrict__ offs, int nb, int n) {
    __shared__ int lds[64];
    int t = threadIdx.x;  // 64 threads
    int v = (t < nb) ? psum[t] : 0;
    lds[t] = v;
    __syncthreads();
    for (int off = 1; off < 64; off <<= 1) {
        int x = lds[t];
        int add = (t >= off) ? lds[t - off] : 0;
        __syncthreads();
        lds[t] = x + add;
        __syncthreads();
    }
    if (t < nb) psum[t] = lds[t] - v;  // exclusive prefix of block sums
    if (t == 63) offs[n] = lds[63];    // grand total
}

__global__ void scan3_kernel(const int* __restrict__ deg, const int* __restrict__ psum,
                             int* __restrict__ offs, int* __restrict__ cursor, int n) {
    __shared__ int lds[256];
    int t = threadIdx.x;
    int base = blockIdx.x * SCAN_CHUNK + t * 8;
    int dv[8];
    int s = 0;
    #pragma unroll
    for (int i = 0; i < 8; i++) {
        int idx = base + i;
        dv[i] = (idx < n) ? deg[idx] + 1 : 0;
        s += dv[i];
    }
    lds[t] = s;
    __syncthreads();
    for (int off = 1; off < 256; off <<= 1) {
        int x = lds[t];
        int add = (t >= off) ? lds[t - off] : 0;
        __syncthreads();
        lds[t] = x + add;
        __syncthreads();
    }
    int run = psum[blockIdx.x] + lds[t] - s;
    #pragma unroll
    for (int i = 0; i < 8; i++) {
        int idx = base + i;
        if (idx < n) { offs[idx] = run; cursor[idx] = run; run += dv[i]; }
    }
}

// packed edge record: .x = src node, .y = bitcast(norm)
__global__ void fill_edges(const int* __restrict__ src, const int* __restrict__ dst,
                           const float* __restrict__ dinv, int* __restrict__ cursor,
                           int2* __restrict__ cpk, int E) {
    int e = blockIdx.x * 256 + threadIdx.x;
    if (e >= E) return;
    int s = src[e], d0 = dst[e];
    int pos = atomicAdd(&cursor[d0], 1);
    cpk[pos] = make_int2(s, __float_as_int(dinv[s] * dinv[d0]));
}

__global__ void fill_self(const float* __restrict__ dinv, int* __restrict__ cursor,
                          int2* __restrict__ cpk, int n) {
    int v = blockIdx.x * 256 + threadIdx.x;
    if (v >= n) return;
    int pos = atomicAdd(&cursor[v], 1);
    float dv = dinv[v];
    cpk[pos] = make_int2(v, __float_as_int(dv * dv));
}

// ---------------- GEMM: C[n,128] = A @ W[128,128] ----------------
__global__ void gemm_kernel(const float* __restrict__ A, const float* __restrict__ W,
                            float* __restrict__ C) {
    __shared__ float Wl[64 * 128];
    int tid = threadIdx.x;
    int rg = tid >> 5, cg = tid & 31;
    size_t row0 = (size_t)blockIdx.x * 32 + rg;  // rows row0 + {0,8,16,24}
    const float4* Wg4 = (const float4*)W;
    const float4* A4 = (const float4*)A;
    float4* Wl4 = (float4*)Wl;
    float4 acc0 = {0.f,0.f,0.f,0.f}, acc1 = acc0, acc2 = acc0, acc3 = acc0;
    for (int half = 0; half < 2; ++half) {
        __syncthreads();
        for (int i = tid; i < 2048; i += 256) Wl4[i] = Wg4[half * 2048 + i];
        __syncthreads();
        #pragma unroll
        for (int kq = 0; kq < 16; ++kq) {
            int kv = half * 16 + kq;
            float4 a0 = A4[(row0 + 0)  * 32 + kv];
            float4 a1 = A4[(row0 + 8)  * 32 + kv];
            float4 a2 = A4[(row0 + 16) * 32 + kv];
            float4 a3 = A4[(row0 + 24) * 32 + kv];
            float a0v[4] = {a0.x, a0.y, a0.z, a0.w};
            float a1v[4] = {a1.x, a1.y, a1.z, a1.w};
            float a2v[4] = {a2.x, a2.y, a2.z, a2.w};
            float a3v[4] = {a3.x, a3.y, a3.z, a3.w};
            #pragma unroll
            for (int j = 0; j < 4; ++j) {
                float4 w = Wl4[(kq * 4 + j) * 32 + cg];
                acc0.x += a0v[j]*w.x; acc0.y += a0v[j]*w.y; acc0.z += a0v[j]*w.z; acc0.w += a0v[j]*w.w;
                acc1.x += a1v[j]*w.x; acc1.y += a1v[j]*w.y; acc1.z += a1v[j]*w.z; acc1.w += a1v[j]*w.w;
                acc2.x += a2v[j]*w.x; acc2.y += a2v[j]*w.y; acc2.z += a2v[j]*w.z; acc2.w += a2v[j]*w.w;
                acc3.x += a3v[j]*w.x; acc3.y += a3v[j]*w.y; acc3.z += a3v[j]*w.z; acc3.w += a3v[j]*w.w;
            }
        }
    }
    float4* C4 = (float4*)C;
    C4[(row0 + 0)  * 32 + cg] = acc0;
    C4[(row0 + 8)  * 32 + cg] = acc1;
    C4[(row0 + 16) * 32 + cg] = acc2;
    C4[(row0 + 24) * 32 + cg] = acc3;
}

// ---------------- CSR aggregation: Out[v] = epilogue(sum norm[i]*H[src[i]]) --------
// One 64-lane wave per node; lane owns feats {2l, 2l+1} (float2 -> one 512B row per
// gather instr). Up to 64 edge records preloaded in ONE coalesced load, then
// broadcast via __shfl -> no record load in the dependency chain. Unroll x4.
template <int BIAS_RELU>
__global__ void agg_kernel(const int* __restrict__ roff, const int2* __restrict__ cpk,
                           const float* __restrict__ H, const float* __restrict__ bias,
                           float* __restrict__ Out) {
    int tid = threadIdx.x;
    int wv = tid >> 6, lane = tid & 63;
    size_t v = (size_t)blockIdx.x * 4 + wv;
    int b = roff[v], e = roff[v + 1];
    const float2* H2 = (const float2*)H;
    float2 acc = {0.f, 0.f};
    for (int base = b; base < e; base += 64) {
        int idx = base + lane;
        if (idx >= e) idx = e - 1;       // clamped dup, never consumed
        int2 rec = cpk[idx];             // one coalesced 512B record load
        int kmax = min(64, e - base);
        int k = 0;
        for (; k + 4 <= kmax; k += 4) {
            int s0 = __shfl(rec.x, k,     64);
            int s1 = __shfl(rec.x, k + 1, 64);
            int s2 = __shfl(rec.x, k + 2, 64);
            int s3 = __shfl(rec.x, k + 3, 64);
            float n0 = __int_as_float(__shfl(rec.y, k,     64));
            float n1 = __int_as_float(__shfl(rec.y, k + 1, 64));
            float n2 = __int_as_float(__shfl(rec.y, k + 2, 64));
            float n3 = __int_as_float(__shfl(rec.y, k + 3, 64));
            float2 h0 = H2[(size_t)s0 * 64 + lane];
            float2 h1 = H2[(size_t)s1 * 64 + lane];
            float2 h2 = H2[(size_t)s2 * 64 + lane];
            float2 h3 = H2[(size_t)s3 * 64 + lane];
            acc.x += n0 * h0.x + n1 * h1.x + n2 * h2.x + n3 * h3.x;
            acc.y += n0 * h0.y + n1 * h1.y + n2 * h2.y + n3 * h3.y;
        }
        for (; k < kmax; k++) {
            int s0 = __shfl(rec.x, k, 64);
            float n0 = __int_as_float(__shfl(rec.y, k, 64));
            float2 h0 = H2[(size_t)s0 * 64 + lane];
            acc.x += n0 * h0.x;
            acc.y += n0 * h0.y;
        }
    }
    if (BIAS_RELU) {
        float2 bb = ((const float2*)bias)[lane];
        acc.x = fmaxf(acc.x + bb.x, 0.f);
        acc.y = fmaxf(acc.y + bb.y, 0.f);
    }
    ((float2*)Out)[v * 64 + lane] = acc;
}

// ---------------- segmented mean-pool (batch sorted) ----------------
__global__ void pool_kernel(const float* __restrict__ H, const int* __restrict__ batch,
                            float* __restrict__ gsum, float* __restrict__ gcnt, int n) {
    __shared__ int bl[128];
    int d = threadIdx.x;
    int base = blockIdx.x * 128;
    int cnt_here = min(128, n - base);
    if (cnt_here <= 0) return;
    if (d < cnt_here) bl[d] = batch[base + d];
    __syncthreads();
    float acc = 0.f;
    int cg = -1, c = 0;
    for (int i = 0; i < cnt_here; i++) {
        int g = bl[i];
        if (g != cg) {
            if (cg >= 0) {
                atomicAdd(&gsum[cg * DF + d], acc);
                if (d == 0) atomicAdd(&gcnt[cg], (float)c);
            }
            acc = 0.f; c = 0; cg = g;
        }
        acc += H[(size_t)(base + i) * DF + d];
        c++;
    }
    if (cg >= 0) {
        atomicAdd(&gsum[cg * DF + d], acc);
        if (d == 0) atomicAdd(&gcnt[cg], (float)c);
    }
}

// ---------------- final: out[g] = dot(gsum[g]/cnt + b2, Wm) + bm ----------------
__global__ void final_kernel(const float* __restrict__ gsum, const float* __restrict__ gcnt,
                             const float* __restrict__ b2, const float* __restrict__ Wm,
                             const float* __restrict__ bm, float* __restrict__ out) {
    __shared__ float red[2];
    int g = blockIdx.x, d = threadIdx.x;
    float cnt = fmaxf(gcnt[g], 1.0f);
    float v = (gsum[g * DF + d] / cnt + b2[d]) * Wm[d];
    for (int off = 32; off > 0; off >>= 1) v += __shfl_down(v, off, 64);
    if ((d & 63) == 0) red[d >> 6] = v;
    __syncthreads();
    if (d == 0) out[g] = red[0] + red[1] + bm[0];
}

extern "C" void kernel_launch(void* const* d_in, const int* in_sizes, int n_in,
                              void* d_out, int out_size, void* d_ws, size_t ws_size,
                              hipStream_t stream) {
    const float* x   = (const float*)d_in[0];
    const int*   ei  = (const int*)d_in[1];   // [2, E] flat: first E = src, next E = dst
    const int*   bat = (const int*)d_in[2];
    const float* W1  = (const float*)d_in[3];
    const float* b1  = (const float*)d_in[4];
    const float* W2  = (const float*)d_in[5];
    const float* b2  = (const float*)d_in[6];
    const float* Wm  = (const float*)d_in[7];
    const float* bm  = (const float*)d_in[8];
    float* out = (float*)d_out;

    const int N = NNODES, E = NEDGES, G = NGRAPH;
    const int* src = ei;
    const int* dst = ei + E;

    // workspace carve
    char* base = (char*)d_ws;
    size_t o = 0;
    auto alloc = [&](size_t bytes) { size_t p = o; o = (o + bytes + 255) & ~(size_t)255; return p; };
    int*   deg    = (int*)(base + alloc((size_t)N * 4));
    int*   cursor = (int*)(base + alloc((size_t)N * 4));
    int*   offs   = (int*)(base + alloc((size_t)(N + 1) * 4));
    float* dinv   = (float*)(base + alloc((size_t)N * 4));
    int*   psum   = (int*)(base + alloc((size_t)NB_SCAN * 4));
    int2*  cpk    = (int2*)(base + alloc((size_t)(E + N) * 8));
    float* bufA   = (float*)(base + alloc((size_t)N * DF * 4));
    float* bufB   = (float*)(base + alloc((size_t)N * DF * 4));
    float* gsum   = (float*)(base + alloc((size_t)G * DF * 4));
    float* gcnt   = (float*)(base + alloc((size_t)G * 4));
    (void)ws_size;

    hipMemsetAsync(deg, 0, (size_t)N * 4, stream);
    hipMemsetAsync(gsum, 0, (size_t)G * DF * 4, stream);
    hipMemsetAsync(gcnt, 0, (size_t)G * 4, stream);

    // CSR build
    deg_kernel<<<(E + 255) / 256, 256, 0, stream>>>(dst, deg, E);
    dinv_kernel<<<(N + 255) / 256, 256, 0, stream>>>(deg, dinv, N);
    scan1_kernel<<<NB_SCAN, 256, 0, stream>>>(deg, psum, N);
    scan2_kernel<<<1, 64, 0, stream>>>(psum, offs, NB_SCAN, N);
    scan3_kernel<<<NB_SCAN, 256, 0, stream>>>(deg, psum, offs, cursor, N);
    fill_edges<<<(E + 255) / 256, 256, 0, stream>>>(src, dst, dinv, cursor, cpk, E);
    fill_self<<<(N + 255) / 256, 256, 0, stream>>>(dinv, cursor, cpk, N);

    // layer 1: bufA = x @ W1 ; bufB = relu(A_hat * bufA + b1)
    gemm_kernel<<<N / 32, 256, 0, stream>>>(x, W1, bufA);
    agg_kernel<1><<<N / 4, 256, 0, stream>>>(offs, cpk, bufA, b1, bufB);

    // layer 2: bufA = bufB @ W2 ; bufB = A_hat * bufA
    gemm_kernel<<<N / 32, 256, 0, stream>>>(bufB, W2, bufA);
    agg_kernel<0><<<N / 4, 256, 0, stream>>>(offs, cpk, bufA, nullptr, bufB);

    // pool + final
    pool_kernel<<<(N + 127) / 128, 128, 0, stream>>>(bufB, bat, gsum, gcnt, N);
    final_kernel<<<G, 128, 0, stream>>>(gsum, gcnt, b2, Wm, bm, out);
}

// Round 5
// 474.846 us; speedup vs baseline: 1.8818x; 1.1875x over previous
//
#include <hip/hip_runtime.h>
#include <hip/hip_bf16.h>

#define NNODES 100000
#define NEDGES 1600000
#define DF 128
#define NGRAPH 256
#define SCAN_CHUNK 2048
#define NB_SCAN ((NNODES + SCAN_CHUNK - 1) / SCAN_CHUNK)

// ---------------- degree count (in-degree over real edges) ----------------
__global__ void deg_kernel(const int* __restrict__ dst, int* __restrict__ deg, int E) {
    int e = blockIdx.x * 256 + threadIdx.x;
    if (e < E) atomicAdd(&deg[dst[e]], 1);
}

// dinv[v] = rsqrt(deg[v] + 1)   (+1 = self loop; always >= 1)
__global__ void dinv_kernel(const int* __restrict__ deg, float* __restrict__ dinv, int n) {
    int v = blockIdx.x * 256 + threadIdx.x;
    if (v < n) dinv[v] = rsqrtf((float)deg[v] + 1.0f);
}

// ---------------- hierarchical scan of (deg[v]+1) -> offs[0..n], cursor ----------------
__global__ void scan1_kernel(const int* __restrict__ deg, int* __restrict__ psum, int n) {
    __shared__ int lds[256];
    int t = threadIdx.x;
    int base = blockIdx.x * SCAN_CHUNK + t * 8;
    int s = 0;
    #pragma unroll
    for (int i = 0; i < 8; i++) { int idx = base + i; if (idx < n) s += deg[idx] + 1; }
    lds[t] = s;
    __syncthreads();
    for (int off = 128; off > 0; off >>= 1) {
        if (t < off) lds[t] += lds[t + off];
        __syncthreads();
    }
    if (t == 0) psum[blockIdx.x] = lds[0];
}

__global__ void scan2_kernel(int* __restrict__ psum, int* __restrict__ offs, int nb, int n) {
    __shared__ int lds[64];
    int t = threadIdx.x;  // 64 threads
    int v = (t < nb) ? psum[t] : 0;
    lds[t] = v;
    __syncthreads();
    for (int off = 1; off < 64; off <<= 1) {
        int x = lds[t];
        int add = (t >= off) ? lds[t - off] : 0;
        __syncthreads();
        lds[t] = x + add;
        __syncthreads();
    }
    if (t < nb) psum[t] = lds[t] - v;  // exclusive prefix of block sums
    if (t == 63) offs[n] = lds[63];    // grand total
}

__global__ void scan3_kernel(const int* __restrict__ deg, const int* __restrict__ psum,
                             int* __restrict__ offs, int* __restrict__ cursor, int n) {
    __shared__ int lds[256];
    int t = threadIdx.x;
    int base = blockIdx.x * SCAN_CHUNK + t * 8;
    int dv[8];
    int s = 0;
    #pragma unroll
    for (int i = 0; i < 8; i++) {
        int idx = base + i;
        dv[i] = (idx < n) ? deg[idx] + 1 : 0;
        s += dv[i];
    }
    lds[t] = s;
    __syncthreads();
    for (int off = 1; off < 256; off <<= 1) {
        int x = lds[t];
        int add = (t >= off) ? lds[t - off] : 0;
        __syncthreads();
        lds[t] = x + add;
        __syncthreads();
    }
    int run = psum[blockIdx.x] + lds[t] - s;
    #pragma unroll
    for (int i = 0; i < 8; i++) {
        int idx = base + i;
        if (idx < n) { offs[idx] = run; cursor[idx] = run; run += dv[i]; }
    }
}

// packed edge record: .x = src node, .y = bitcast(norm)
__global__ void fill_edges(const int* __restrict__ src, const int* __restrict__ dst,
                           const float* __restrict__ dinv, int* __restrict__ cursor,
                           int2* __restrict__ cpk, int E) {
    int e = blockIdx.x * 256 + threadIdx.x;
    if (e >= E) return;
    int s = src[e], d0 = dst[e];
    int pos = atomicAdd(&cursor[d0], 1);
    cpk[pos] = make_int2(s, __float_as_int(dinv[s] * dinv[d0]));
}

__global__ void fill_self(const float* __restrict__ dinv, int* __restrict__ cursor,
                          int2* __restrict__ cpk, int n) {
    int v = blockIdx.x * 256 + threadIdx.x;
    if (v >= n) return;
    int pos = atomicAdd(&cursor[v], 1);
    float dv = dinv[v];
    cpk[pos] = make_int2(v, __float_as_int(dv * dv));
}

// RNE pack: two f32 -> bf16x2 (lo = a, hi = b)
__device__ __forceinline__ unsigned int pack_bf16x2(float a, float b) {
    unsigned int ua = __float_as_uint(a);
    unsigned int ub = __float_as_uint(b);
    ua += 0x7fffu + ((ua >> 16) & 1u);
    ub += 0x7fffu + ((ub >> 16) & 1u);
    return (ua >> 16) | (ub & 0xffff0000u);
}

// ---------------- GEMM: C_bf16[n,128] = A @ W[128,128] ----------------
// block = 256 threads covering 32 rows; each thread: 4 rows x 4 cols.
__global__ void gemm_kernel(const float* __restrict__ A, const float* __restrict__ W,
                            unsigned int* __restrict__ C) {  // C: bf16x2 words, row stride 64
    __shared__ float Wl[64 * 128];
    int tid = threadIdx.x;
    int rg = tid >> 5, cg = tid & 31;
    size_t row0 = (size_t)blockIdx.x * 32 + rg;  // rows row0 + {0,8,16,24}
    const float4* Wg4 = (const float4*)W;
    const float4* A4 = (const float4*)A;
    float4* Wl4 = (float4*)Wl;
    float4 acc0 = {0.f,0.f,0.f,0.f}, acc1 = acc0, acc2 = acc0, acc3 = acc0;
    for (int half = 0; half < 2; ++half) {
        __syncthreads();
        for (int i = tid; i < 2048; i += 256) Wl4[i] = Wg4[half * 2048 + i];
        __syncthreads();
        #pragma unroll
        for (int kq = 0; kq < 16; ++kq) {
            int kv = half * 16 + kq;
            float4 a0 = A4[(row0 + 0)  * 32 + kv];
            float4 a1 = A4[(row0 + 8)  * 32 + kv];
            float4 a2 = A4[(row0 + 16) * 32 + kv];
            float4 a3 = A4[(row0 + 24) * 32 + kv];
            float a0v[4] = {a0.x, a0.y, a0.z, a0.w};
            float a1v[4] = {a1.x, a1.y, a1.z, a1.w};
            float a2v[4] = {a2.x, a2.y, a2.z, a2.w};
            float a3v[4] = {a3.x, a3.y, a3.z, a3.w};
            #pragma unroll
            for (int j = 0; j < 4; ++j) {
                float4 w = Wl4[(kq * 4 + j) * 32 + cg];
                acc0.x += a0v[j]*w.x; acc0.y += a0v[j]*w.y; acc0.z += a0v[j]*w.z; acc0.w += a0v[j]*w.w;
                acc1.x += a1v[j]*w.x; acc1.y += a1v[j]*w.y; acc1.z += a1v[j]*w.z; acc1.w += a1v[j]*w.w;
                acc2.x += a2v[j]*w.x; acc2.y += a2v[j]*w.y; acc2.z += a2v[j]*w.z; acc2.w += a2v[j]*w.w;
                acc3.x += a3v[j]*w.x; acc3.y += a3v[j]*w.y; acc3.z += a3v[j]*w.z; acc3.w += a3v[j]*w.w;
            }
        }
    }
    // epilogue: round to bf16, write uint2 (4 bf16) per row
    uint2* C2 = (uint2*)C;  // row stride = 32 uint2
    uint2 o0 = make_uint2(pack_bf16x2(acc0.x, acc0.y), pack_bf16x2(acc0.z, acc0.w));
    uint2 o1 = make_uint2(pack_bf16x2(acc1.x, acc1.y), pack_bf16x2(acc1.z, acc1.w));
    uint2 o2 = make_uint2(pack_bf16x2(acc2.x, acc2.y), pack_bf16x2(acc2.z, acc2.w));
    uint2 o3 = make_uint2(pack_bf16x2(acc3.x, acc3.y), pack_bf16x2(acc3.z, acc3.w));
    C2[(row0 + 0)  * 32 + cg] = o0;
    C2[(row0 + 8)  * 32 + cg] = o1;
    C2[(row0 + 16) * 32 + cg] = o2;
    C2[(row0 + 24) * 32 + cg] = o3;
}

// ---------------- CSR aggregation: Out[v] = epilogue(sum norm[i]*H[src[i]]) --------
// One 64-lane wave per node; H is bf16 (row = 256B); lane owns feats {2l, 2l+1}
// (one uint = bf16x2 per gather). Records preloaded coalesced + shfl broadcast.
// Unroll x8 -> 8 independent 256B row-gathers in flight.
template <int BIAS_RELU>
__global__ void agg_kernel(const int* __restrict__ roff, const int2* __restrict__ cpk,
                           const unsigned int* __restrict__ Hb, const float* __restrict__ bias,
                           float* __restrict__ Out) {
    int tid = threadIdx.x;
    int wv = tid >> 6, lane = tid & 63;
    size_t v = (size_t)blockIdx.x * 4 + wv;
    int b = roff[v], e = roff[v + 1];
    float2 acc = {0.f, 0.f};
    for (int base = b; base < e; base += 64) {
        int idx = base + lane;
        if (idx >= e) idx = e - 1;       // clamped dup, never consumed
        int2 rec = cpk[idx];             // one coalesced 512B record load
        int kmax = min(64, e - base);
        int k = 0;
        for (; k + 8 <= kmax; k += 8) {
            unsigned int u[8];
            float nn[8];
            #pragma unroll
            for (int j = 0; j < 8; j++) {
                int s = __shfl(rec.x, k + j, 64);
                nn[j] = __int_as_float(__shfl(rec.y, k + j, 64));
                u[j] = Hb[(size_t)s * 64 + lane];
            }
            #pragma unroll
            for (int j = 0; j < 8; j++) {
                float lo = __uint_as_float(u[j] << 16);
                float hi = __uint_as_float(u[j] & 0xffff0000u);
                acc.x += nn[j] * lo;
                acc.y += nn[j] * hi;
            }
        }
        for (; k < kmax; k++) {
            int s = __shfl(rec.x, k, 64);
            float n0 = __int_as_float(__shfl(rec.y, k, 64));
            unsigned int u0 = Hb[(size_t)s * 64 + lane];
            acc.x += n0 * __uint_as_float(u0 << 16);
            acc.y += n0 * __uint_as_float(u0 & 0xffff0000u);
        }
    }
    if (BIAS_RELU) {
        float2 bb = ((const float2*)bias)[lane];
        acc.x = fmaxf(acc.x + bb.x, 0.f);
        acc.y = fmaxf(acc.y + bb.y, 0.f);
    }
    ((float2*)Out)[v * 64 + lane] = acc;
}

// ---------------- segmented mean-pool (batch sorted) ----------------
__global__ void pool_kernel(const float* __restrict__ H, const int* __restrict__ batch,
                            float* __restrict__ gsum, float* __restrict__ gcnt, int n) {
    __shared__ int bl[128];
    int d = threadIdx.x;
    int base = blockIdx.x * 128;
    int cnt_here = min(128, n - base);
    if (cnt_here <= 0) return;
    if (d < cnt_here) bl[d] = batch[base + d];
    __syncthreads();
    float acc = 0.f;
    int cg = -1, c = 0;
    for (int i = 0; i < cnt_here; i++) {
        int g = bl[i];
        if (g != cg) {
            if (cg >= 0) {
                atomicAdd(&gsum[cg * DF + d], acc);
                if (d == 0) atomicAdd(&gcnt[cg], (float)c);
            }
            acc = 0.f; c = 0; cg = g;
        }
        acc += H[(size_t)(base + i) * DF + d];
        c++;
    }
    if (cg >= 0) {
        atomicAdd(&gsum[cg * DF + d], acc);
        if (d == 0) atomicAdd(&gcnt[cg], (float)c);
    }
}

// ---------------- final: out[g] = dot(gsum[g]/cnt + b2, Wm) + bm ----------------
__global__ void final_kernel(const float* __restrict__ gsum, const float* __restrict__ gcnt,
                             const float* __restrict__ b2, const float* __restrict__ Wm,
                             const float* __restrict__ bm, float* __restrict__ out) {
    __shared__ float red[2];
    int g = blockIdx.x, d = threadIdx.x;
    float cnt = fmaxf(gcnt[g], 1.0f);
    float v = (gsum[g * DF + d] / cnt + b2[d]) * Wm[d];
    for (int off = 32; off > 0; off >>= 1) v += __shfl_down(v, off, 64);
    if ((d & 63) == 0) red[d >> 6] = v;
    __syncthreads();
    if (d == 0) out[g] = red[0] + red[1] + bm[0];
}

extern "C" void kernel_launch(void* const* d_in, const int* in_sizes, int n_in,
                              void* d_out, int out_size, void* d_ws, size_t ws_size,
                              hipStream_t stream) {
    const float* x   = (const float*)d_in[0];
    const int*   ei  = (const int*)d_in[1];   // [2, E] flat: first E = src, next E = dst
    const int*   bat = (const int*)d_in[2];
    const float* W1  = (const float*)d_in[3];
    const float* b1  = (const float*)d_in[4];
    const float* W2  = (const float*)d_in[5];
    const float* b2  = (const float*)d_in[6];
    const float* Wm  = (const float*)d_in[7];
    const float* bm  = (const float*)d_in[8];
    float* out = (float*)d_out;

    const int N = NNODES, E = NEDGES, G = NGRAPH;
    const int* src = ei;
    const int* dst = ei + E;

    // workspace carve
    char* base = (char*)d_ws;
    size_t o = 0;
    auto alloc = [&](size_t bytes) { size_t p = o; o = (o + bytes + 255) & ~(size_t)255; return p; };
    int*   deg    = (int*)(base + alloc((size_t)N * 4));
    int*   cursor = (int*)(base + alloc((size_t)N * 4));
    int*   offs   = (int*)(base + alloc((size_t)(N + 1) * 4));
    float* dinv   = (float*)(base + alloc((size_t)N * 4));
    int*   psum   = (int*)(base + alloc((size_t)NB_SCAN * 4));
    int2*  cpk    = (int2*)(base + alloc((size_t)(E + N) * 8));
    unsigned int* bufH = (unsigned int*)(base + alloc((size_t)N * DF * 2));  // bf16 H
    float* bufB   = (float*)(base + alloc((size_t)N * DF * 4));
    float* gsum   = (float*)(base + alloc((size_t)G * DF * 4));
    float* gcnt   = (float*)(base + alloc((size_t)G * 4));
    (void)ws_size;

    hipMemsetAsync(deg, 0, (size_t)N * 4, stream);
    hipMemsetAsync(gsum, 0, (size_t)G * DF * 4, stream);
    hipMemsetAsync(gcnt, 0, (size_t)G * 4, stream);

    // CSR build
    deg_kernel<<<(E + 255) / 256, 256, 0, stream>>>(dst, deg, E);
    dinv_kernel<<<(N + 255) / 256, 256, 0, stream>>>(deg, dinv, N);
    scan1_kernel<<<NB_SCAN, 256, 0, stream>>>(deg, psum, N);
    scan2_kernel<<<1, 64, 0, stream>>>(psum, offs, NB_SCAN, N);
    scan3_kernel<<<NB_SCAN, 256, 0, stream>>>(deg, psum, offs, cursor, N);
    fill_edges<<<(E + 255) / 256, 256, 0, stream>>>(src, dst, dinv, cursor, cpk, E);
    fill_self<<<(N + 255) / 256, 256, 0, stream>>>(dinv, cursor, cpk, N);

    // layer 1: bufH = bf16(x @ W1) ; bufB = relu(A_hat * bufH + b1)
    gemm_kernel<<<N / 32, 256, 0, stream>>>(x, W1, bufH);
    agg_kernel<1><<<N / 4, 256, 0, stream>>>(offs, cpk, bufH, b1, bufB);

    // layer 2: bufH = bf16(bufB @ W2) ; bufB = A_hat * bufH
    gemm_kernel<<<N / 32, 256, 0, stream>>>(bufB, W2, bufH);
    agg_kernel<0><<<N / 4, 256, 0, stream>>>(offs, cpk, bufH, nullptr, bufB);

    // pool + final
    pool_kernel<<<(N + 127) / 128, 128, 0, stream>>>(bufB, bat, gsum, gcnt, N);
    final_kernel<<<G, 128, 0, stream>>>(gsum, gcnt, b2, Wm, bm, out);
}

// Round 6
// 395.988 us; speedup vs baseline: 2.2565x; 1.1991x over previous
//
#include <hip/hip_runtime.h>
#include <hip/hip_bf16.h>

#define NNODES 100000
#define NEDGES 1600000
#define DF 128
#define NGRAPH 256
#define SCAN_CHUNK 2048
#define NB_SCAN ((NNODES + SCAN_CHUNK - 1) / SCAN_CHUNK)

typedef __attribute__((ext_vector_type(8))) short short8;
typedef __attribute__((ext_vector_type(4))) float f32x4;

// ---------------- degree count (in-degree over real edges) ----------------
__global__ void deg_kernel(const int* __restrict__ dst, int* __restrict__ deg, int E) {
    int e = blockIdx.x * 256 + threadIdx.x;
    if (e < E) atomicAdd(&deg[dst[e]], 1);
}

// dinv[v] = rsqrt(deg[v] + 1)   (+1 = self loop; always >= 1)
__global__ void dinv_kernel(const int* __restrict__ deg, float* __restrict__ dinv, int n) {
    int v = blockIdx.x * 256 + threadIdx.x;
    if (v < n) dinv[v] = rsqrtf((float)deg[v] + 1.0f);
}

// ---------------- hierarchical scan of (deg[v]+1) -> offs[0..n], cursor ----------------
__global__ void scan1_kernel(const int* __restrict__ deg, int* __restrict__ psum, int n) {
    __shared__ int lds[256];
    int t = threadIdx.x;
    int base = blockIdx.x * SCAN_CHUNK + t * 8;
    int s = 0;
    #pragma unroll
    for (int i = 0; i < 8; i++) { int idx = base + i; if (idx < n) s += deg[idx] + 1; }
    lds[t] = s;
    __syncthreads();
    for (int off = 128; off > 0; off >>= 1) {
        if (t < off) lds[t] += lds[t + off];
        __syncthreads();
    }
    if (t == 0) psum[blockIdx.x] = lds[0];
}

__global__ void scan2_kernel(int* __restrict__ psum, int* __restrict__ offs, int nb, int n) {
    __shared__ int lds[64];
    int t = threadIdx.x;  // 64 threads
    int v = (t < nb) ? psum[t] : 0;
    lds[t] = v;
    __syncthreads();
    for (int off = 1; off < 64; off <<= 1) {
        int x = lds[t];
        int add = (t >= off) ? lds[t - off] : 0;
        __syncthreads();
        lds[t] = x + add;
        __syncthreads();
    }
    if (t < nb) psum[t] = lds[t] - v;  // exclusive prefix of block sums
    if (t == 63) offs[n] = lds[63];    // grand total
}

__global__ void scan3_kernel(const int* __restrict__ deg, const int* __restrict__ psum,
                             int* __restrict__ offs, int* __restrict__ cursor, int n) {
    __shared__ int lds[256];
    int t = threadIdx.x;
    int base = blockIdx.x * SCAN_CHUNK + t * 8;
    int dv[8];
    int s = 0;
    #pragma unroll
    for (int i = 0; i < 8; i++) {
        int idx = base + i;
        dv[i] = (idx < n) ? deg[idx] + 1 : 0;
        s += dv[i];
    }
    lds[t] = s;
    __syncthreads();
    for (int off = 1; off < 256; off <<= 1) {
        int x = lds[t];
        int add = (t >= off) ? lds[t - off] : 0;
        __syncthreads();
        lds[t] = x + add;
        __syncthreads();
    }
    int run = psum[blockIdx.x] + lds[t] - s;
    #pragma unroll
    for (int i = 0; i < 8; i++) {
        int idx = base + i;
        if (idx < n) { offs[idx] = run; cursor[idx] = run; run += dv[i]; }
    }
}

// packed edge record: .x = src node, .y = bitcast(norm)
__global__ void fill_edges(const int* __restrict__ src, const int* __restrict__ dst,
                           const float* __restrict__ dinv, int* __restrict__ cursor,
                           int2* __restrict__ cpk, int E) {
    int e = blockIdx.x * 256 + threadIdx.x;
    if (e >= E) return;
    int s = src[e], d0 = dst[e];
    int pos = atomicAdd(&cursor[d0], 1);
    cpk[pos] = make_int2(s, __float_as_int(dinv[s] * dinv[d0]));
}

__global__ void fill_self(const float* __restrict__ dinv, int* __restrict__ cursor,
                          int2* __restrict__ cpk, int n) {
    int v = blockIdx.x * 256 + threadIdx.x;
    if (v >= n) return;
    int pos = atomicAdd(&cursor[v], 1);
    float dv = dinv[v];
    cpk[pos] = make_int2(v, __float_as_int(dv * dv));
}

// RNE pack: two f32 -> bf16x2 (lo = a, hi = b)
__device__ __forceinline__ unsigned int pack_bf16x2(float a, float b) {
    unsigned int ua = __float_as_uint(a);
    unsigned int ub = __float_as_uint(b);
    ua += 0x7fffu + ((ua >> 16) & 1u);
    ub += 0x7fffu + ((ub >> 16) & 1u);
    return (ua >> 16) | (ub & 0xffff0000u);
}

// split f32 -> (hi bf16, lo bf16): w ~= hi + lo, error ~2^-17 relative
__device__ __forceinline__ void split_bf16(float w, unsigned short& h, unsigned short& l) {
    unsigned int uw = __float_as_uint(w);
    unsigned int hb = uw + 0x7fffu + ((uw >> 16) & 1u);
    h = (unsigned short)(hb >> 16);
    float rem = w - __uint_as_float((unsigned int)h << 16);
    unsigned int ur = __float_as_uint(rem);
    unsigned int lb = ur + 0x7fffu + ((ur >> 16) & 1u);
    l = (unsigned short)(lb >> 16);
}

// ---------------- W prep: frag-major split-bf16 layout ----------------
// Frag (t,q), lane, i  ->  W[32q + 8*(lane>>4) + i][16t + (lane&15)]
// stored at [(t*4+q)*64 + lane]*8 + i  (ushort). 2048 threads, one frag-lane each.
__global__ void wprep_kernel(const float* __restrict__ W, unsigned short* __restrict__ Wh,
                             unsigned short* __restrict__ Wl) {
    int id = blockIdx.x * 256 + threadIdx.x;  // 0..2047
    if (id >= 2048) return;
    int lane = id & 63, tq = id >> 6;
    int t = tq >> 2, q = tq & 3;
    int n = 16 * t + (lane & 15);
    int kbase = 32 * q + 8 * (lane >> 4);
    unsigned short h[8], l[8];
    #pragma unroll
    for (int i = 0; i < 8; i++) {
        split_bf16(W[(kbase + i) * DF + n], h[i], l[i]);
    }
    uint4 hv, lv;
    hv.x = h[0] | ((unsigned int)h[1] << 16); hv.y = h[2] | ((unsigned int)h[3] << 16);
    hv.z = h[4] | ((unsigned int)h[5] << 16); hv.w = h[6] | ((unsigned int)h[7] << 16);
    lv.x = l[0] | ((unsigned int)l[1] << 16); lv.y = l[2] | ((unsigned int)l[3] << 16);
    lv.z = l[4] | ((unsigned int)l[5] << 16); lv.w = l[6] | ((unsigned int)l[7] << 16);
    ((uint4*)Wh)[id] = hv;
    ((uint4*)Wl)[id] = lv;
}

// ---------------- MFMA GEMM: C_bf16[n,128] = A_f32[n,128] @ W[128,128] -------------
// Split-precision: A = ah+al, W = wh+wl; acc += ah*wh + al*wh + ah*wl  (~fp32 quality).
// Operand order: W-frag is the M(16 feat)xK operand, node-rows are the KxN operand,
// so D: col(lane&15) = node row, regs = 4 consecutive features -> lane-local bf16 pack.
// 4 waves/block, 16 rows/wave, no LDS.
__global__ void gemm_mfma(const float* __restrict__ A, const unsigned short* __restrict__ Wh,
                          const unsigned short* __restrict__ Wl, unsigned int* __restrict__ C,
                          int nrows) {
    int tid = threadIdx.x;
    int wv = tid >> 6, lane = tid & 63;
    int c16 = lane & 15, g = lane >> 4;
    int row = blockIdx.x * 64 + wv * 16 + c16;
    int rowc = min(row, nrows - 1);
    const float4* A4 = (const float4*)A;
    const short8* Wh8 = (const short8*)Wh;
    const short8* Wl8 = (const short8*)Wl;
    f32x4 acc[8];
    #pragma unroll
    for (int t = 0; t < 8; t++) acc[t] = (f32x4){0.f, 0.f, 0.f, 0.f};
    #pragma unroll
    for (int q = 0; q < 4; q++) {
        // lane reads A[row][32q + 8g .. +8): two float4
        float4 a0 = A4[(size_t)rowc * 32 + q * 8 + g * 2];
        float4 a1 = A4[(size_t)rowc * 32 + q * 8 + g * 2 + 1];
        float av[8] = {a0.x, a0.y, a0.z, a0.w, a1.x, a1.y, a1.z, a1.w};
        short8 ah, al;
        #pragma unroll
        for (int i = 0; i < 8; i++) {
            unsigned short hs, ls;
            split_bf16(av[i], hs, ls);
            ah[i] = (short)hs;
            al[i] = (short)ls;
        }
        #pragma unroll
        for (int t = 0; t < 8; t++) {
            short8 wh = Wh8[(t * 4 + q) * 64 + lane];
            short8 wl = Wl8[(t * 4 + q) * 64 + lane];
            acc[t] = __builtin_amdgcn_mfma_f32_16x16x32_bf16(wh, ah, acc[t], 0, 0, 0);
            acc[t] = __builtin_amdgcn_mfma_f32_16x16x32_bf16(wh, al, acc[t], 0, 0, 0);
            acc[t] = __builtin_amdgcn_mfma_f32_16x16x32_bf16(wl, ah, acc[t], 0, 0, 0);
        }
    }
    if (row < nrows) {
        uint2* C2 = (uint2*)C;
        #pragma unroll
        for (int t = 0; t < 8; t++) {
            // lane owns features 16t+4g+{0..3} of node `row`
            uint2 w;
            w.x = pack_bf16x2(acc[t][0], acc[t][1]);
            w.y = pack_bf16x2(acc[t][2], acc[t][3]);
            C2[(size_t)row * 32 + t * 4 + g] = w;
        }
    }
}

// ---------------- CSR aggregation: Out[v] = epilogue(sum norm[i]*H[src[i]]) --------
// One 64-lane wave per node; H is bf16 (row = 256B); lane owns feats {2l, 2l+1}.
template <int BIAS_RELU>
__global__ void agg_kernel(const int* __restrict__ roff, const int2* __restrict__ cpk,
                           const unsigned int* __restrict__ Hb, const float* __restrict__ bias,
                           float* __restrict__ Out) {
    int tid = threadIdx.x;
    int wv = tid >> 6, lane = tid & 63;
    size_t v = (size_t)blockIdx.x * 4 + wv;
    int b = roff[v], e = roff[v + 1];
    float2 acc = {0.f, 0.f};
    for (int base = b; base < e; base += 64) {
        int idx = base + lane;
        if (idx >= e) idx = e - 1;       // clamped dup, never consumed
        int2 rec = cpk[idx];             // one coalesced 512B record load
        int kmax = min(64, e - base);
        int k = 0;
        for (; k + 8 <= kmax; k += 8) {
            unsigned int u[8];
            float nn[8];
            #pragma unroll
            for (int j = 0; j < 8; j++) {
                int s = __shfl(rec.x, k + j, 64);
                nn[j] = __int_as_float(__shfl(rec.y, k + j, 64));
                u[j] = Hb[(size_t)s * 64 + lane];
            }
            #pragma unroll
            for (int j = 0; j < 8; j++) {
                float lo = __uint_as_float(u[j] << 16);
                float hi = __uint_as_float(u[j] & 0xffff0000u);
                acc.x += nn[j] * lo;
                acc.y += nn[j] * hi;
            }
        }
        for (; k < kmax; k++) {
            int s = __shfl(rec.x, k, 64);
            float n0 = __int_as_float(__shfl(rec.y, k, 64));
            unsigned int u0 = Hb[(size_t)s * 64 + lane];
            acc.x += n0 * __uint_as_float(u0 << 16);
            acc.y += n0 * __uint_as_float(u0 & 0xffff0000u);
        }
    }
    if (BIAS_RELU) {
        float2 bb = ((const float2*)bias)[lane];
        acc.x = fmaxf(acc.x + bb.x, 0.f);
        acc.y = fmaxf(acc.y + bb.y, 0.f);
    }
    ((float2*)Out)[v * 64 + lane] = acc;
}

// ---------------- segmented mean-pool (batch sorted) ----------------
__global__ void pool_kernel(const float* __restrict__ H, const int* __restrict__ batch,
                            float* __restrict__ gsum, float* __restrict__ gcnt, int n) {
    __shared__ int bl[128];
    int d = threadIdx.x;
    int base = blockIdx.x * 128;
    int cnt_here = min(128, n - base);
    if (cnt_here <= 0) return;
    if (d < cnt_here) bl[d] = batch[base + d];
    __syncthreads();
    float acc = 0.f;
    int cg = -1, c = 0;
    for (int i = 0; i < cnt_here; i++) {
        int g = bl[i];
        if (g != cg) {
            if (cg >= 0) {
                atomicAdd(&gsum[cg * DF + d], acc);
                if (d == 0) atomicAdd(&gcnt[cg], (float)c);
            }
            acc = 0.f; c = 0; cg = g;
        }
        acc += H[(size_t)(base + i) * DF + d];
        c++;
    }
    if (cg >= 0) {
        atomicAdd(&gsum[cg * DF + d], acc);
        if (d == 0) atomicAdd(&gcnt[cg], (float)c);
    }
}

// ---------------- final: out[g] = dot(gsum[g]/cnt + b2, Wm) + bm ----------------
__global__ void final_kernel(const float* __restrict__ gsum, const float* __restrict__ gcnt,
                             const float* __restrict__ b2, const float* __restrict__ Wm,
                             const float* __restrict__ bm, float* __restrict__ out) {
    __shared__ float red[2];
    int g = blockIdx.x, d = threadIdx.x;
    float cnt = fmaxf(gcnt[g], 1.0f);
    float v = (gsum[g * DF + d] / cnt + b2[d]) * Wm[d];
    for (int off = 32; off > 0; off >>= 1) v += __shfl_down(v, off, 64);
    if ((d & 63) == 0) red[d >> 6] = v;
    __syncthreads();
    if (d == 0) out[g] = red[0] + red[1] + bm[0];
}

extern "C" void kernel_launch(void* const* d_in, const int* in_sizes, int n_in,
                              void* d_out, int out_size, void* d_ws, size_t ws_size,
                              hipStream_t stream) {
    const float* x   = (const float*)d_in[0];
    const int*   ei  = (const int*)d_in[1];   // [2, E] flat: first E = src, next E = dst
    const int*   bat = (const int*)d_in[2];
    const float* W1  = (const float*)d_in[3];
    const float* b1  = (const float*)d_in[4];
    const float* W2  = (const float*)d_in[5];
    const float* b2  = (const float*)d_in[6];
    const float* Wm  = (const float*)d_in[7];
    const float* bm  = (const float*)d_in[8];
    float* out = (float*)d_out;

    const int N = NNODES, E = NEDGES, G = NGRAPH;
    const int* src = ei;
    const int* dst = ei + E;

    // workspace carve
    char* base = (char*)d_ws;
    size_t o = 0;
    auto alloc = [&](size_t bytes) { size_t p = o; o = (o + bytes + 255) & ~(size_t)255; return p; };
    int*   deg    = (int*)(base + alloc((size_t)N * 4));
    int*   cursor = (int*)(base + alloc((size_t)N * 4));
    int*   offs   = (int*)(base + alloc((size_t)(N + 1) * 4));
    float* dinv   = (float*)(base + alloc((size_t)N * 4));
    int*   psum   = (int*)(base + alloc((size_t)NB_SCAN * 4));
    int2*  cpk    = (int2*)(base + alloc((size_t)(E + N) * 8));
    unsigned int* bufH = (unsigned int*)(base + alloc((size_t)N * DF * 2));  // bf16 H
    float* bufB   = (float*)(base + alloc((size_t)N * DF * 4));
    float* gsum   = (float*)(base + alloc((size_t)G * DF * 4));
    float* gcnt   = (float*)(base + alloc((size_t)G * 4));
    unsigned short* wh1 = (unsigned short*)(base + alloc(2048 * 16));
    unsigned short* wl1 = (unsigned short*)(base + alloc(2048 * 16));
    unsigned short* wh2 = (unsigned short*)(base + alloc(2048 * 16));
    unsigned short* wl2 = (unsigned short*)(base + alloc(2048 * 16));
    (void)ws_size;

    hipMemsetAsync(deg, 0, (size_t)N * 4, stream);
    hipMemsetAsync(gsum, 0, (size_t)G * DF * 4, stream);
    hipMemsetAsync(gcnt, 0, (size_t)G * 4, stream);

    // CSR build
    deg_kernel<<<(E + 255) / 256, 256, 0, stream>>>(dst, deg, E);
    dinv_kernel<<<(N + 255) / 256, 256, 0, stream>>>(deg, dinv, N);
    scan1_kernel<<<NB_SCAN, 256, 0, stream>>>(deg, psum, N);
    scan2_kernel<<<1, 64, 0, stream>>>(psum, offs, NB_SCAN, N);
    scan3_kernel<<<NB_SCAN, 256, 0, stream>>>(deg, psum, offs, cursor, N);
    fill_edges<<<(E + 255) / 256, 256, 0, stream>>>(src, dst, dinv, cursor, cpk, E);
    fill_self<<<(N + 255) / 256, 256, 0, stream>>>(dinv, cursor, cpk, N);

    // W prep (tiny)
    wprep_kernel<<<8, 256, 0, stream>>>(W1, wh1, wl1);
    wprep_kernel<<<8, 256, 0, stream>>>(W2, wh2, wl2);

    // layer 1: bufH = bf16(x @ W1) ; bufB = relu(A_hat * bufH + b1)
    gemm_mfma<<<(N + 63) / 64, 256, 0, stream>>>(x, wh1, wl1, bufH, N);
    agg_kernel<1><<<N / 4, 256, 0, stream>>>(offs, cpk, bufH, b1, bufB);

    // layer 2: bufH = bf16(bufB @ W2) ; bufB = A_hat * bufH
    gemm_mfma<<<(N + 63) / 64, 256, 0, stream>>>(bufB, wh2, wl2, bufH, N);
    agg_kernel<0><<<N / 4, 256, 0, stream>>>(offs, cpk, bufH, nullptr, bufB);

    // pool + final
    pool_kernel<<<(N + 127) / 128, 128, 0, stream>>>(bufB, bat, gsum, gcnt, N);
    final_kernel<<<G, 128, 0, stream>>>(gsum, gcnt, b2, Wm, bm, out);
}